// Round 2
// baseline (560.479 us; speedup 1.0000x reference)
//
#include <hip/hip_runtime.h>

// ---- problem constants ----
#define TT 2048      // tokens (2*1024)
#define DM 1024      // d_model
#define FF 2048      // d_ff
#define NE 7         // routed experts
#define NSLOT 6144   // 2*TT routed assignments + TT shared
#define H_LD 4096    // h row stride (2F)

typedef short bf16x8 __attribute__((ext_vector_type(8)));
typedef float f32x4 __attribute__((ext_vector_type(4)));

__device__ __forceinline__ unsigned short f2bf(float f) {
  union { float f; unsigned int u; } v; v.f = f;
  unsigned int r = v.u + 0x7fffu + ((v.u >> 16) & 1u);  // RNE
  return (unsigned short)(r >> 16);
}
__device__ __forceinline__ float bf2f(unsigned short s) {
  union { unsigned int u; float f; } v; v.u = ((unsigned int)s) << 16;
  return v.f;
}

// ---- x fp32 -> bf16 ----
__global__ __launch_bounds__(256) void convert_x_kernel(
    const float* __restrict__ x, unsigned short* __restrict__ xb) {
  int i = (blockIdx.x * 256 + threadIdx.x) * 8;
  float4 a = *(const float4*)(x + i);
  float4 b = *(const float4*)(x + i + 4);
  bf16x8 o;
  o[0]=(short)f2bf(a.x); o[1]=(short)f2bf(a.y); o[2]=(short)f2bf(a.z); o[3]=(short)f2bf(a.w);
  o[4]=(short)f2bf(b.x); o[5]=(short)f2bf(b.y); o[6]=(short)f2bf(b.z); o[7]=(short)f2bf(b.w);
  *(bf16x8*)(xb + i) = o;
}

// ---- router: logits, softmax, top-2, lists + aux sums ----
__global__ __launch_bounds__(256) void router_kernel(
    const float* __restrict__ x, const float* __restrict__ rw,
    int* __restrict__ cnt, float* __restrict__ probsum,
    int* __restrict__ idxl, float* __restrict__ gwl) {
  __shared__ float ps[NE];
  int tid = threadIdx.x;
  if (tid < NE) ps[tid] = 0.f;
  __syncthreads();
  int wave = tid >> 6, lane = tid & 63;
  int t = blockIdx.x * 4 + wave;           // grid 512 -> t < 2048
  float xv[16];
#pragma unroll
  for (int i = 0; i < 16; ++i) xv[i] = x[(size_t)t * DM + lane + i * 64];
  float lg[NE];
#pragma unroll
  for (int e = 0; e < NE; ++e) {
    float s = 0.f;
#pragma unroll
    for (int i = 0; i < 16; ++i) s += xv[i] * rw[e * DM + lane + i * 64];
#pragma unroll
    for (int o = 32; o > 0; o >>= 1) s += __shfl_xor(s, o);
    lg[e] = s;                              // all lanes hold full logit
  }
  float m = lg[0];
#pragma unroll
  for (int e = 1; e < NE; ++e) m = fmaxf(m, lg[e]);
  float p[NE]; float sum = 0.f;
#pragma unroll
  for (int e = 0; e < NE; ++e) { p[e] = expf(lg[e] - m); sum += p[e]; }
  float inv = 1.f / sum;
  int i1 = 0; float v1 = p[0];
#pragma unroll
  for (int e = 1; e < NE; ++e) if (p[e] > v1) { v1 = p[e]; i1 = e; }
  int i2 = -1; float v2 = -1.f;
#pragma unroll
  for (int e = 0; e < NE; ++e) if (e != i1 && p[e] > v2) { v2 = p[e]; i2 = e; }
  float g1 = v1 / (v1 + v2), g2 = v2 / (v1 + v2);   // renormalized gates
  if (lane == 0) {
#pragma unroll
    for (int e = 0; e < NE; ++e) atomicAdd(&ps[e], p[e] * inv);
    int pos = atomicAdd(&cnt[i1], 1); idxl[i1 * TT + pos] = t; gwl[i1 * TT + pos] = g1;
    pos = atomicAdd(&cnt[i2], 1);     idxl[i2 * TT + pos] = t; gwl[i2 * TT + pos] = g2;
    idxl[NE * TT + t] = t; gwl[NE * TT + t] = 1.0f;  // shared-expert identity list
  }
  __syncthreads();
  if (tid < NE) atomicAdd(&probsum[tid], ps[tid]);
}

// ---- offsets + aux loss ----
__global__ void finalize_kernel(int* __restrict__ cnt, int* __restrict__ offs,
                                const float* __restrict__ probsum,
                                float* __restrict__ aux_out) {
  if (threadIdx.x == 0) {
    int o = 0;
    for (int e = 0; e < NE; ++e) { offs[e] = o; o += cnt[e]; }
    offs[NE] = o;            // == 2*TT
    cnt[NE] = TT;            // shared expert
    double s = 0.0;
    for (int e = 0; e < NE; ++e) s += (double)cnt[e] * (double)probsum[e];
    // aux = 0.01 * E * sum_e (cnt_e/(T*K)) * (probsum_e/T)
    aux_out[0] = (float)(0.01 * 7.0 * s / (4096.0 * 2048.0));
  }
}

// ---- compact capacity-layout lists -> slot-contiguous ----
__global__ __launch_bounds__(256) void compact_kernel(
    const int* __restrict__ cnt, const int* __restrict__ offs,
    const int* __restrict__ idxl, const float* __restrict__ gwl,
    int* __restrict__ token_s, float* __restrict__ gate_s) {
  int j = blockIdx.x * 256 + threadIdx.x;   // < 8*TT
  int e = j >> 11, pos = j & 2047;
  if (pos < cnt[e]) {
    int s = offs[e] + pos;
    token_s[s] = idxl[j];
    gate_s[s] = gwl[j];
  }
}

// ---- grouped GEMM: C[m][n] = sum_k A[m][k]*B[n][k]  (B^T form) ----
// MODE 0: A = xb gathered by token list, writes h (bf16)
// MODE 1: A = h rows (act), atomic-scatter fp32 into y by token
template <int MODE>
__global__ __launch_bounds__(256) void moe_gemm_kernel(
    const unsigned short* __restrict__ Abase,
    const float* __restrict__ Bw_routed, const float* __restrict__ Bw_shared,
    unsigned short* __restrict__ Hout, float* __restrict__ Yout,
    const int* __restrict__ cnt, const int* __restrict__ offs,
    const int* __restrict__ token_s, int N, int K, int lda) {
  __shared__ unsigned short As[128 * 32];
  __shared__ unsigned short Bs[128 * 32];
  const int e = blockIdx.z;
  const int cnt_e = cnt[e];
  const int m0 = blockIdx.y * 128;
  if (m0 >= cnt_e) return;
  const int off_e = offs[e];
  const int n0 = blockIdx.x * 128;
  const float* Bw = (e == NE) ? Bw_shared : Bw_routed + (size_t)e * N * K;

  const int tid = threadIdx.x;
  const int wave = tid >> 6, lane = tid & 63;

  // staging assignment: thread -> (row = tid>>1, k-half = tid&1), 16 elems each
  const int srow = tid >> 1, kh = tid & 1;
  int rr = min(m0 + srow, cnt_e - 1);
  int slot = off_e + rr;
  int arow = (MODE == 0) ? token_s[slot] : slot;
  const unsigned short* ap = Abase + (size_t)arow * lda + kh * 16;
  const float* bp = Bw + (size_t)(n0 + srow) * K + kh * 16;
  unsigned short* adst = &As[srow * 32 + kh * 16];
  unsigned short* bdst = &Bs[srow * 32 + kh * 16];

  f32x4 acc[4][4];
#pragma unroll
  for (int m = 0; m < 4; ++m)
#pragma unroll
    for (int n = 0; n < 4; ++n) acc[m][n] = (f32x4){0.f, 0.f, 0.f, 0.f};

  const int wr = wave >> 1, wc = wave & 1;
  const int lr = lane & 15, lh = lane >> 4;

  for (int k0 = 0; k0 < K; k0 += 32) {
    __syncthreads();                       // prev compute done before overwrite
    bf16x8 a0 = *(const bf16x8*)(ap + k0);
    bf16x8 a1 = *(const bf16x8*)(ap + k0 + 8);
    float4 b0 = *(const float4*)(bp + k0);
    float4 b1 = *(const float4*)(bp + k0 + 4);
    float4 b2 = *(const float4*)(bp + k0 + 8);
    float4 b3 = *(const float4*)(bp + k0 + 12);
    *(bf16x8*)adst = a0;
    *(bf16x8*)(adst + 8) = a1;
    bf16x8 w0, w1;
    w0[0]=(short)f2bf(b0.x); w0[1]=(short)f2bf(b0.y); w0[2]=(short)f2bf(b0.z); w0[3]=(short)f2bf(b0.w);
    w0[4]=(short)f2bf(b1.x); w0[5]=(short)f2bf(b1.y); w0[6]=(short)f2bf(b1.z); w0[7]=(short)f2bf(b1.w);
    w1[0]=(short)f2bf(b2.x); w1[1]=(short)f2bf(b2.y); w1[2]=(short)f2bf(b2.z); w1[3]=(short)f2bf(b2.w);
    w1[4]=(short)f2bf(b3.x); w1[5]=(short)f2bf(b3.y); w1[6]=(short)f2bf(b3.z); w1[7]=(short)f2bf(b3.w);
    *(bf16x8*)bdst = w0;
    *(bf16x8*)(bdst + 8) = w1;
    __syncthreads();                       // staging visible
    bf16x8 af[4], bfv[4];
#pragma unroll
    for (int m = 0; m < 4; ++m)
      af[m] = *(const bf16x8*)&As[(wr * 64 + m * 16 + lr) * 32 + lh * 8];
#pragma unroll
    for (int n = 0; n < 4; ++n)
      bfv[n] = *(const bf16x8*)&Bs[(wc * 64 + n * 16 + lr) * 32 + lh * 8];
#pragma unroll
    for (int m = 0; m < 4; ++m)
#pragma unroll
      for (int n = 0; n < 4; ++n)
        acc[m][n] = __builtin_amdgcn_mfma_f32_16x16x32_bf16(af[m], bfv[n], acc[m][n], 0, 0, 0);
  }

  // epilogue: C/D layout col=lane&15, row=(lane>>4)*4+j  [m89/m91-verified]
#pragma unroll
  for (int m = 0; m < 4; ++m) {
#pragma unroll
    for (int j = 0; j < 4; ++j) {
      int r = wr * 64 + m * 16 + lh * 4 + j;
      int gm = m0 + r;
      if (gm < cnt_e) {
        if (MODE == 0) {
          size_t base = (size_t)(off_e + gm) * H_LD + n0;
#pragma unroll
          for (int n = 0; n < 4; ++n)
            Hout[base + wc * 64 + n * 16 + lr] = (unsigned short)(short)f2bf(acc[m][n][j]);
        } else {
          int tok = token_s[off_e + gm];
          size_t base = (size_t)tok * DM + n0;
#pragma unroll
          for (int n = 0; n < 4; ++n)
            atomicAdd(&Yout[base + wc * 64 + n * 16 + lr], acc[m][n][j]);
        }
      }
    }
  }
}

// ---- SwiGLU + gate, in place into first F columns of h ----
__global__ __launch_bounds__(256) void swiglu_kernel(
    unsigned short* __restrict__ h, const float* __restrict__ gate_s) {
  int slot = blockIdx.x;
  float gate = gate_s[slot];
  unsigned short* row = h + (size_t)slot * H_LD;
  int f0 = threadIdx.x * 8;
  bf16x8 gv = *(const bf16x8*)(row + f0);
  bf16x8 uv = *(const bf16x8*)(row + f0 + FF);
  bf16x8 o;
#pragma unroll
  for (int j = 0; j < 8; ++j) {
    float g = bf2f((unsigned short)gv[j]);
    float u = bf2f((unsigned short)uv[j]);
    float sg = g / (1.f + __expf(-g));
    o[j] = (short)f2bf(sg * u * gate);
  }
  *(bf16x8*)(row + f0) = o;
}

extern "C" void kernel_launch(void* const* d_in, const int* in_sizes, int n_in,
                              void* d_out, int out_size, void* d_ws, size_t ws_size,
                              hipStream_t stream) {
  const float* x     = (const float*)d_in[0];   // [2,1024,1024]
  const float* rw    = (const float*)d_in[1];   // [7,1024]
  const float* cfc   = (const float*)d_in[2];   // [7,4096,1024]
  const float* cproj = (const float*)d_in[3];   // [7,1024,2048]
  const float* sfc   = (const float*)d_in[4];   // [4096,1024]
  const float* sproj = (const float*)d_in[5];   // [1024,2048]
  float* out = (float*)d_out;                   // y[2097152] + aux[1]

  char* w = (char*)d_ws;
  unsigned short* xb = (unsigned short*)w; w += (size_t)TT * DM * 2;       // 4 MB
  unsigned short* h  = (unsigned short*)w; w += (size_t)NSLOT * H_LD * 2;  // 50.3 MB
  int*   idxl    = (int*)w;   w += (size_t)8 * TT * 4;
  float* gwl     = (float*)w; w += (size_t)8 * TT * 4;
  int*   token_s = (int*)w;   w += (size_t)NSLOT * 4;
  float* gate_s  = (float*)w; w += (size_t)NSLOT * 4;
  int*   cnt     = (int*)w;   w += 32;
  float* probsum = (float*)w; w += 32;
  int*   offs    = (int*)w;   w += 32;

  hipMemsetAsync(d_out, 0, (size_t)out_size * sizeof(float), stream);
  hipMemsetAsync(cnt, 0, 64, stream);   // cnt + probsum contiguous

  convert_x_kernel<<<1024, 256, 0, stream>>>(x, xb);
  router_kernel<<<512, 256, 0, stream>>>(x, rw, cnt, probsum, idxl, gwl);
  finalize_kernel<<<1, 64, 0, stream>>>(cnt, offs, probsum, out + 2097152);
  compact_kernel<<<64, 256, 0, stream>>>(cnt, offs, idxl, gwl, token_s, gate_s);
  // FC: N=4096, K=1024, A = xb (lda=1024)
  moe_gemm_kernel<0><<<dim3(32, 16, 8), 256, 0, stream>>>(
      xb, cfc, sfc, h, nullptr, cnt, offs, token_s, 4096, 1024, 1024);
  swiglu_kernel<<<NSLOT, 256, 0, stream>>>(h, gate_s);
  // DOWN: N=1024, K=2048, A = h/act (lda=4096)
  moe_gemm_kernel<1><<<dim3(8, 16, 8), 256, 0, stream>>>(
      h, cproj, sproj, nullptr, out, cnt, offs, token_s, 1024, 2048, 4096);
}

// Round 5
// 465.995 us; speedup vs baseline: 1.2028x; 1.2028x over previous
//
#include <hip/hip_runtime.h>

// ---- problem constants ----
#define TT 2048      // tokens (2*1024)
#define DM 1024      // d_model
#define FF 2048      // d_ff
#define NE 7         // routed experts
#define NSLOT 6144   // 2*TT routed assignments + TT shared
#define H_LD 4096    // legacy h row stride (2F)

typedef short bf16x8 __attribute__((ext_vector_type(8)));
typedef float f32x4 __attribute__((ext_vector_type(4)));

__device__ __forceinline__ unsigned short f2bf(float f) {
  union { float f; unsigned int u; } v; v.f = f;
  unsigned int r = v.u + 0x7fffu + ((v.u >> 16) & 1u);  // RNE
  return (unsigned short)(r >> 16);
}
__device__ __forceinline__ float bf2f(unsigned short s) {
  union { unsigned int u; float f; } v; v.u = ((unsigned int)s) << 16;
  return v.f;
}

// async global->LDS, 16B per lane; dst must be wave-uniform base (+lane*16 HW)
#define GLDS16(gp, lp)                                                        \
  __builtin_amdgcn_global_load_lds(                                           \
      (const __attribute__((address_space(1))) void*)(gp),                    \
      (__attribute__((address_space(3))) void*)(lp), 16, 0, 0)

// ---- fp32 -> bf16 bulk convert (count in vec8 units, grid exact) ----
__global__ __launch_bounds__(256) void convert_kernel(
    const float* __restrict__ src, unsigned short* __restrict__ dst) {
  size_t i = ((size_t)blockIdx.x * 256 + threadIdx.x) * 8;
  float4 a = *(const float4*)(src + i);
  float4 b = *(const float4*)(src + i + 4);
  bf16x8 o;
  o[0]=(short)f2bf(a.x); o[1]=(short)f2bf(a.y); o[2]=(short)f2bf(a.z); o[3]=(short)f2bf(a.w);
  o[4]=(short)f2bf(b.x); o[5]=(short)f2bf(b.y); o[6]=(short)f2bf(b.z); o[7]=(short)f2bf(b.w);
  *(bf16x8*)(dst + i) = o;
}

// ---- router: logits, softmax, top-2, lists + aux sums ----
__global__ __launch_bounds__(256) void router_kernel(
    const float* __restrict__ x, const float* __restrict__ rw,
    int* __restrict__ cnt, float* __restrict__ probsum,
    int* __restrict__ idxl, float* __restrict__ gwl) {
  __shared__ float ps[NE];
  int tid = threadIdx.x;
  if (tid < NE) ps[tid] = 0.f;
  __syncthreads();
  int wave = tid >> 6, lane = tid & 63;
  int t = blockIdx.x * 4 + wave;           // grid 512 -> t < 2048
  float xv[16];
#pragma unroll
  for (int i = 0; i < 16; ++i) xv[i] = x[(size_t)t * DM + lane + i * 64];
  float lg[NE];
#pragma unroll
  for (int e = 0; e < NE; ++e) {
    float s = 0.f;
#pragma unroll
    for (int i = 0; i < 16; ++i) s += xv[i] * rw[e * DM + lane + i * 64];
#pragma unroll
    for (int o = 32; o > 0; o >>= 1) s += __shfl_xor(s, o);
    lg[e] = s;
  }
  float m = lg[0];
#pragma unroll
  for (int e = 1; e < NE; ++e) m = fmaxf(m, lg[e]);
  float p[NE]; float sum = 0.f;
#pragma unroll
  for (int e = 0; e < NE; ++e) { p[e] = expf(lg[e] - m); sum += p[e]; }
  float inv = 1.f / sum;
  int i1 = 0; float v1 = p[0];
#pragma unroll
  for (int e = 1; e < NE; ++e) if (p[e] > v1) { v1 = p[e]; i1 = e; }
  int i2 = -1; float v2 = -1.f;
#pragma unroll
  for (int e = 0; e < NE; ++e) if (e != i1 && p[e] > v2) { v2 = p[e]; i2 = e; }
  float g1 = v1 / (v1 + v2), g2 = v2 / (v1 + v2);
  if (lane == 0) {
#pragma unroll
    for (int e = 0; e < NE; ++e) atomicAdd(&ps[e], p[e] * inv);
    int pos = atomicAdd(&cnt[i1], 1); idxl[i1 * TT + pos] = t; gwl[i1 * TT + pos] = g1;
    pos = atomicAdd(&cnt[i2], 1);     idxl[i2 * TT + pos] = t; gwl[i2 * TT + pos] = g2;
    idxl[NE * TT + t] = t; gwl[NE * TT + t] = 1.0f;
  }
  __syncthreads();
  if (tid < NE) atomicAdd(&probsum[tid], ps[tid]);
}

// ---- offsets + aux loss ----
__global__ void finalize_kernel(int* __restrict__ cnt, int* __restrict__ offs,
                                const float* __restrict__ probsum,
                                float* __restrict__ aux_out) {
  if (threadIdx.x == 0) {
    int o = 0;
    for (int e = 0; e < NE; ++e) { offs[e] = o; o += cnt[e]; }
    offs[NE] = o;            // == 2*TT == 4096
    cnt[NE] = TT;            // shared expert
    double s = 0.0;
    for (int e = 0; e < NE; ++e) s += (double)cnt[e] * (double)probsum[e];
    aux_out[0] = (float)(0.01 * 7.0 * s / (4096.0 * 2048.0));
  }
}

// ---- compact capacity-layout lists -> slot-contiguous ----
__global__ __launch_bounds__(256) void compact_kernel(
    const int* __restrict__ cnt, const int* __restrict__ offs,
    const int* __restrict__ idxl, const float* __restrict__ gwl,
    int* __restrict__ token_s, float* __restrict__ gate_s) {
  int j = blockIdx.x * 256 + threadIdx.x;   // < 8*TT
  int e = j >> 11, pos = j & 2047;
  if (pos < cnt[e]) {
    int s = offs[e] + pos;
    token_s[s] = idxl[j];
    gate_s[s] = gwl[j];
  }
}

// ============================================================================
// m97-structure grouped GEMM, bf16 operands via global_load_lds (16B).
// MODE 0 (FC+SwiGLU fused): A = xb gathered by token list (lda=1024), K=1024.
//   B tile rows 0..63 = gate rows (cfc row nb*64+r), 64..127 = up rows
//   (cfc row 2048+nb*64+(r-64)). Epilogue: act = silu(g)*u*gate -> bf16.
// MODE 1 (down): A = act rows (lda=2048), K=2048, BN=64 cols; fp32 atomicAdd
//   scatter into y by token.
// ============================================================================
template <int MODE>
__global__ __launch_bounds__(256) void moe_gemm2_kernel(
    const unsigned short* __restrict__ Abase,
    const unsigned short* __restrict__ Wb,   // 8-expert contiguous bf16 weights
    unsigned short* __restrict__ ActOut, float* __restrict__ Yout,
    const int* __restrict__ cnt, const int* __restrict__ offs,
    const int* __restrict__ token_s, const float* __restrict__ gate_s) {
  constexpr int NB = (MODE == 0) ? 8 : 4;          // B col-fragments per wave
  constexpr int BROWS = NB * 16;                   // B tile rows (128 / 64)
  constexpr int K = (MODE == 0) ? 1024 : 2048;
  constexpr int LDA = (MODE == 0) ? 1024 : 2048;
  constexpr int WSTRIDE = (MODE == 0) ? 4096 * 1024 : 1024 * 2048;

  __shared__ unsigned short As[128 * 32];
  __shared__ unsigned short Bs[BROWS * 32];

  const int e = blockIdx.z;
  const int cnt_e = cnt[e];
  const int m0 = blockIdx.y * 128;
  if (m0 >= cnt_e) return;
  const int off_e = offs[e];
  const int nb = blockIdx.x;
  const unsigned short* Bw = Wb + (size_t)e * WSTRIDE;

  const int tid = threadIdx.x;
  const int w = tid >> 6, l = tid & 63;
  const int kq = l & 3;                 // 16B chunk within 64B row
  const int lsub = l >> 2;              // row within 16-row stage chunk

  // ---- per-thread staging sources (fixed across K loop) ----
  const unsigned short* aSrc0;
  const unsigned short* aSrc1;
  {
    int r0 = w * 32 + lsub, r1 = r0 + 16;
    int rr0 = min(m0 + r0, cnt_e - 1), rr1 = min(m0 + r1, cnt_e - 1);
    int arow0 = (MODE == 0) ? token_s[off_e + rr0] : (off_e + rr0);
    int arow1 = (MODE == 0) ? token_s[off_e + rr1] : (off_e + rr1);
    aSrc0 = Abase + (size_t)arow0 * LDA + kq * 8;
    aSrc1 = Abase + (size_t)arow1 * LDA + kq * 8;
  }
  unsigned short* aDst0 = &As[(w * 32) * 32];
  unsigned short* aDst1 = &As[(w * 32 + 16) * 32];

  const unsigned short* bSrc0;
  const unsigned short* bSrc1 = nullptr;
  unsigned short* bDst0;
  unsigned short* bDst1 = nullptr;
  if (MODE == 0) {
    int r0 = w * 32 + lsub, r1 = r0 + 16;
    int w0 = (r0 < 64) ? nb * 64 + r0 : 2048 + nb * 64 + (r0 - 64);
    int w1 = (r1 < 64) ? nb * 64 + r1 : 2048 + nb * 64 + (r1 - 64);
    bSrc0 = Bw + (size_t)w0 * K + kq * 8;
    bSrc1 = Bw + (size_t)w1 * K + kq * 8;
    bDst0 = &Bs[(w * 32) * 32];
    bDst1 = &Bs[(w * 32 + 16) * 32];
  } else {
    int r0 = w * 16 + lsub;
    bSrc0 = Bw + (size_t)(nb * 64 + r0) * K + kq * 8;
    bDst0 = &Bs[(w * 16) * 32];
  }

  f32x4 acc[2][NB];
#pragma unroll
  for (int m = 0; m < 2; ++m)
#pragma unroll
    for (int n = 0; n < NB; ++n) acc[m][n] = (f32x4){0.f, 0.f, 0.f, 0.f};

  const int lr = l & 15, lh = l >> 4;

  for (int k0 = 0; k0 < K; k0 += 32) {
    __syncthreads();                      // prev compute done before overwrite
    GLDS16(aSrc0 + k0, aDst0);
    GLDS16(aSrc1 + k0, aDst1);
    GLDS16(bSrc0 + k0, bDst0);
    if (MODE == 0) GLDS16(bSrc1 + k0, bDst1);
    __syncthreads();                      // compiler drains vmcnt before barrier
    bf16x8 af[2], bfv[NB];
#pragma unroll
    for (int m = 0; m < 2; ++m)
      af[m] = *(const bf16x8*)&As[(w * 32 + m * 16 + lr) * 32 + lh * 8];
#pragma unroll
    for (int n = 0; n < NB; ++n)
      bfv[n] = *(const bf16x8*)&Bs[(n * 16 + lr) * 32 + lh * 8];
#pragma unroll
    for (int m = 0; m < 2; ++m)
#pragma unroll
      for (int n = 0; n < NB; ++n)
        acc[m][n] = __builtin_amdgcn_mfma_f32_16x16x32_bf16(af[m], bfv[n], acc[m][n], 0, 0, 0);
  }

  // epilogue: C/D layout col=lane&15, row=(lane>>4)*4+j  [m89/m91-verified]
#pragma unroll
  for (int m = 0; m < 2; ++m) {
#pragma unroll
    for (int j = 0; j < 4; ++j) {
      int r = w * 32 + m * 16 + lh * 4 + j;
      int gm = m0 + r;
      if (gm < cnt_e) {
        if (MODE == 0) {
          float gate = gate_s[off_e + gm];
          size_t base = (size_t)(off_e + gm) * FF + nb * 64;
#pragma unroll
          for (int n = 0; n < 4; ++n) {
            float g = acc[m][n][j], u = acc[m][n + 4][j];
            float sg = g / (1.f + __expf(-g));
            ActOut[base + n * 16 + lr] = f2bf(sg * u * gate);
          }
        } else {
          int tok = token_s[off_e + gm];
          size_t base = (size_t)tok * DM + nb * 64;
#pragma unroll
          for (int n = 0; n < 4; ++n)
            atomicAdd(&Yout[base + n * 16 + lr], acc[m][n][j]);
        }
      }
    }
  }
}

// ============================================================================
// legacy fallback path (round-2 proven, ~56 MB ws) — used only if ws too small
// ============================================================================
template <int MODE>
__global__ __launch_bounds__(256) void legacy_gemm_kernel(
    const unsigned short* __restrict__ Abase,
    const float* __restrict__ Bw_routed, const float* __restrict__ Bw_shared,
    unsigned short* __restrict__ Hout, float* __restrict__ Yout,
    const int* __restrict__ cnt, const int* __restrict__ offs,
    const int* __restrict__ token_s, int N, int K, int lda) {
  __shared__ unsigned short As[128 * 32];
  __shared__ unsigned short Bs[128 * 32];
  const int e = blockIdx.z;
  const int cnt_e = cnt[e];
  const int m0 = blockIdx.y * 128;
  if (m0 >= cnt_e) return;
  const int off_e = offs[e];
  const int n0 = blockIdx.x * 128;
  const float* Bw = (e == NE) ? Bw_shared : Bw_routed + (size_t)e * N * K;
  const int tid = threadIdx.x;
  const int wave = tid >> 6, lane = tid & 63;
  const int srow = tid >> 1, kh = tid & 1;
  int rr = min(m0 + srow, cnt_e - 1);
  int slot = off_e + rr;
  int arow = (MODE == 0) ? token_s[slot] : slot;
  const unsigned short* ap = Abase + (size_t)arow * lda + kh * 16;
  const float* bp = Bw + (size_t)(n0 + srow) * K + kh * 16;
  unsigned short* adst = &As[srow * 32 + kh * 16];
  unsigned short* bdst = &Bs[srow * 32 + kh * 16];
  f32x4 acc[4][4];
#pragma unroll
  for (int m = 0; m < 4; ++m)
#pragma unroll
    for (int n = 0; n < 4; ++n) acc[m][n] = (f32x4){0.f, 0.f, 0.f, 0.f};
  const int wr = wave >> 1, wc = wave & 1;
  const int lr = lane & 15, lh = lane >> 4;
  for (int k0 = 0; k0 < K; k0 += 32) {
    __syncthreads();
    bf16x8 a0 = *(const bf16x8*)(ap + k0);
    bf16x8 a1 = *(const bf16x8*)(ap + k0 + 8);
    float4 b0 = *(const float4*)(bp + k0);
    float4 b1 = *(const float4*)(bp + k0 + 4);
    float4 b2 = *(const float4*)(bp + k0 + 8);
    float4 b3 = *(const float4*)(bp + k0 + 12);
    *(bf16x8*)adst = a0;
    *(bf16x8*)(adst + 8) = a1;
    bf16x8 w0, w1;
    w0[0]=(short)f2bf(b0.x); w0[1]=(short)f2bf(b0.y); w0[2]=(short)f2bf(b0.z); w0[3]=(short)f2bf(b0.w);
    w0[4]=(short)f2bf(b1.x); w0[5]=(short)f2bf(b1.y); w0[6]=(short)f2bf(b1.z); w0[7]=(short)f2bf(b1.w);
    w1[0]=(short)f2bf(b2.x); w1[1]=(short)f2bf(b2.y); w1[2]=(short)f2bf(b2.z); w1[3]=(short)f2bf(b2.w);
    w1[4]=(short)f2bf(b3.x); w1[5]=(short)f2bf(b3.y); w1[6]=(short)f2bf(b3.z); w1[7]=(short)f2bf(b3.w);
    *(bf16x8*)bdst = w0;
    *(bf16x8*)(bdst + 8) = w1;
    __syncthreads();
    bf16x8 af[4], bfv[4];
#pragma unroll
    for (int m = 0; m < 4; ++m)
      af[m] = *(const bf16x8*)&As[(wr * 64 + m * 16 + lr) * 32 + lh * 8];
#pragma unroll
    for (int n = 0; n < 4; ++n)
      bfv[n] = *(const bf16x8*)&Bs[(wc * 64 + n * 16 + lr) * 32 + lh * 8];
#pragma unroll
    for (int m = 0; m < 4; ++m)
#pragma unroll
      for (int n = 0; n < 4; ++n)
        acc[m][n] = __builtin_amdgcn_mfma_f32_16x16x32_bf16(af[m], bfv[n], acc[m][n], 0, 0, 0);
  }
#pragma unroll
  for (int m = 0; m < 4; ++m) {
#pragma unroll
    for (int j = 0; j < 4; ++j) {
      int r = wr * 64 + m * 16 + lh * 4 + j;
      int gm = m0 + r;
      if (gm < cnt_e) {
        if (MODE == 0) {
          size_t base = (size_t)(off_e + gm) * H_LD + n0;
#pragma unroll
          for (int n = 0; n < 4; ++n)
            Hout[base + wc * 64 + n * 16 + lr] = (unsigned short)(short)f2bf(acc[m][n][j]);
        } else {
          int tok = token_s[off_e + gm];
          size_t base = (size_t)tok * DM + n0;
#pragma unroll
          for (int n = 0; n < 4; ++n)
            atomicAdd(&Yout[base + wc * 64 + n * 16 + lr], acc[m][n][j]);
        }
      }
    }
  }
}

__global__ __launch_bounds__(256) void legacy_swiglu_kernel(
    unsigned short* __restrict__ h, const float* __restrict__ gate_s) {
  int slot = blockIdx.x;
  float gate = gate_s[slot];
  unsigned short* row = h + (size_t)slot * H_LD;
  int f0 = threadIdx.x * 8;
  bf16x8 gv = *(const bf16x8*)(row + f0);
  bf16x8 uv = *(const bf16x8*)(row + f0 + FF);
  bf16x8 o;
#pragma unroll
  for (int j = 0; j < 8; ++j) {
    float g = bf2f((unsigned short)gv[j]);
    float u = bf2f((unsigned short)uv[j]);
    float sg = g / (1.f + __expf(-g));
    o[j] = (short)f2bf(sg * u * gate);
  }
  *(bf16x8*)(row + f0) = o;
}

extern "C" void kernel_launch(void* const* d_in, const int* in_sizes, int n_in,
                              void* d_out, int out_size, void* d_ws, size_t ws_size,
                              hipStream_t stream) {
  const float* x     = (const float*)d_in[0];   // [2,1024,1024]
  const float* rw    = (const float*)d_in[1];   // [7,1024]
  const float* cfc   = (const float*)d_in[2];   // [7,4096,1024]
  const float* cproj = (const float*)d_in[3];   // [7,1024,2048]
  const float* sfc   = (const float*)d_in[4];   // [4096,1024]
  const float* sproj = (const float*)d_in[5];   // [1024,2048]
  float* out = (float*)d_out;                   // y[2097152] + aux[1]

  // ---- new-path workspace layout (~130.3 MB) ----
  const size_t SZ_XB  = (size_t)TT * DM * 2;              //  4.19 MB
  const size_t SZ_WFC = (size_t)8 * 4096 * 1024 * 2;      // 67.11 MB (cfc + sfc)
  const size_t SZ_WPJ = (size_t)8 * 1024 * 2048 * 2;      // 33.55 MB (cproj + sproj)
  const size_t SZ_ACT = (size_t)NSLOT * FF * 2;           // 25.17 MB
  const size_t SZ_LISTS = (size_t)8 * TT * 8 + (size_t)NSLOT * 8 + 384;
  const size_t need_new = SZ_XB + SZ_WFC + SZ_WPJ + SZ_ACT + SZ_LISTS;

  hipMemsetAsync(d_out, 0, (size_t)out_size * sizeof(float), stream);

  if (ws_size >= need_new) {
    char* w = (char*)d_ws;
    unsigned short* xb    = (unsigned short*)w; w += SZ_XB;
    unsigned short* wfc_b = (unsigned short*)w; w += SZ_WFC;
    unsigned short* wpj_b = (unsigned short*)w; w += SZ_WPJ;
    unsigned short* act   = (unsigned short*)w; w += SZ_ACT;
    int*   idxl    = (int*)w;   w += (size_t)8 * TT * 4;
    float* gwl     = (float*)w; w += (size_t)8 * TT * 4;
    int*   token_s = (int*)w;   w += (size_t)NSLOT * 4;
    float* gate_s  = (float*)w; w += (size_t)NSLOT * 4;
    int*   cnt     = (int*)w;   w += 32;
    float* probsum = (float*)w; w += 32;
    int*   offs    = (int*)w;   w += 32;

    hipMemsetAsync(cnt, 0, 64, stream);   // cnt + probsum contiguous

    // weight + activation bf16 conversion (grid = elems/2048 each)
    convert_kernel<<<1024, 256, 0, stream>>>(x, xb);
    convert_kernel<<<14336, 256, 0, stream>>>(cfc, wfc_b);
    convert_kernel<<<2048, 256, 0, stream>>>(sfc, wfc_b + (size_t)7 * 4096 * 1024);
    convert_kernel<<<7168, 256, 0, stream>>>(cproj, wpj_b);
    convert_kernel<<<1024, 256, 0, stream>>>(sproj, wpj_b + (size_t)7 * 1024 * 2048);

    router_kernel<<<512, 256, 0, stream>>>(x, rw, cnt, probsum, idxl, gwl);
    finalize_kernel<<<1, 64, 0, stream>>>(cnt, offs, probsum, out + 2097152);
    compact_kernel<<<64, 256, 0, stream>>>(cnt, offs, idxl, gwl, token_s, gate_s);

    // FC + fused SwiGLU: grid x=32 (64 act cols each), y=16 m-blocks, z=8 experts
    moe_gemm2_kernel<0><<<dim3(32, 16, 8), 256, 0, stream>>>(
        xb, wfc_b, act, nullptr, cnt, offs, token_s, gate_s);
    // Down: grid x=16 (64 y cols each)
    moe_gemm2_kernel<1><<<dim3(16, 16, 8), 256, 0, stream>>>(
        act, wpj_b, nullptr, out, cnt, offs, token_s, gate_s);
  } else {
    // ---- legacy round-2 path (~56 MB ws) ----
    char* w = (char*)d_ws;
    unsigned short* xb = (unsigned short*)w; w += (size_t)TT * DM * 2;
    unsigned short* h  = (unsigned short*)w; w += (size_t)NSLOT * H_LD * 2;
    int*   idxl    = (int*)w;   w += (size_t)8 * TT * 4;
    float* gwl     = (float*)w; w += (size_t)8 * TT * 4;
    int*   token_s = (int*)w;   w += (size_t)NSLOT * 4;
    float* gate_s  = (float*)w; w += (size_t)NSLOT * 4;
    int*   cnt     = (int*)w;   w += 32;
    float* probsum = (float*)w; w += 32;
    int*   offs    = (int*)w;   w += 32;

    hipMemsetAsync(cnt, 0, 64, stream);
    convert_kernel<<<1024, 256, 0, stream>>>(x, xb);
    router_kernel<<<512, 256, 0, stream>>>(x, rw, cnt, probsum, idxl, gwl);
    finalize_kernel<<<1, 64, 0, stream>>>(cnt, offs, probsum, out + 2097152);
    compact_kernel<<<64, 256, 0, stream>>>(cnt, offs, idxl, gwl, token_s, gate_s);
    legacy_gemm_kernel<0><<<dim3(32, 16, 8), 256, 0, stream>>>(
        xb, cfc, sfc, h, nullptr, cnt, offs, token_s, 4096, 1024, 1024);
    legacy_swiglu_kernel<<<NSLOT, 256, 0, stream>>>(h, gate_s);
    legacy_gemm_kernel<1><<<dim3(8, 16, 8), 256, 0, stream>>>(
        h, cproj, sproj, nullptr, out, cnt, offs, token_s, 1024, 2048, 4096);
  }
}